// Round 10
// baseline (138.832 us; speedup 1.0000x reference)
//
#include <hip/hip_runtime.h>
#include <hip/hip_bf16.h>

// ScaledDotProdAttn (no softmax): attn = (q@k^T)/8 ; out = attn@v
// B=32, SQ=SK=2048, D=64, fp32 in/out. d_out = [out] ++ [attn]
// R10: key-split waves (4 qgroups x 2 key-halves). QK^T via 32x32x16
//      (an = S, key-in-lanes -> direct fp32 attn stores, R8-proven).
//      PV via 16x16x32 over the wave's 32-key half (R5-proven frags),
//      S_w wave-private in LDS. Per-wave LDS frag reads halved vs R5.
//      End-of-kernel O reduce across key-half pairs. Staging/swizzles/
//      XCD-map/lgkm-barrier verbatim from R5/R9.

typedef __attribute__((ext_vector_type(4)))  float        f32x4;
typedef __attribute__((ext_vector_type(16))) float        f32x16;
typedef __attribute__((ext_vector_type(8)))  short        s16x8;

#define NB    32
#define SQL   2048
#define SKL   2048
#define DD    64
#define QBLK  128
#define KBLK  64
#define NTILES (SKL / KBLK)

// LDS (48 KB -> 2 blocks/CU, 16 waves/CU; grid caps at 2 blocks/CU anyway):
//   [0    ,16384) K dbuf : 2 x (64 keys x 64 bf16), row stride 128 B, swzK
//   [16384,32768) V^T dbuf: 2 x (64 d x 64 keys bf16), row stride 128 B, swzV
//   [32768,49152) S priv : 8 waves x (32 q x 32 k bf16), row stride 64 B, swzS
//   epilogue: [0,32768) reused as 4 x 8 KB fp32 O-reduce scratch (per qw)
#define KOFF 0
#define VOFF 16384
#define SOFF 32768

__device__ __forceinline__ unsigned short f2bf(float f) {
    union { float f; unsigned u; } x; x.f = f;
    unsigned r = x.u + 0x7FFFu + ((x.u >> 16) & 1u);   // RNE
    return (unsigned short)(r >> 16);
}
// K/V swizzles (R5-proven). S swizzle: XOR byte bit 5 with q-bit-2 so the
// two q-rows of one write instr land in different 16-bank groups.
__device__ __forceinline__ unsigned swzK(unsigned k) { return (k & 7u) << 4; }
__device__ __forceinline__ unsigned swzV(unsigned d) { return (d & 7u) << 4; }
__device__ __forceinline__ unsigned swzS(unsigned q) { return ((q >> 2) & 1u) << 5; }

// Workgroup barrier draining LDS only (R9: same perf, keeps stores lazy).
__device__ __forceinline__ void bar_lds() {
    asm volatile("s_waitcnt lgkmcnt(0)" ::: "memory");
    __builtin_amdgcn_s_barrier();
    asm volatile("" ::: "memory");
}

__global__ __launch_bounds__(512, 4)
void sdpa_fused(const float* __restrict__ qg, const float* __restrict__ kg,
                const float* __restrict__ vg, float* __restrict__ og,
                float* __restrict__ ag) {
    __shared__ __align__(16) char smem[49152];

    const unsigned tid  = threadIdx.x;
    const unsigned wid  = tid >> 6;          // 0..7
    const unsigned lane = tid & 63u;
    const unsigned l15  = lane & 15u;
    const unsigned l4   = lane >> 4;         // 0..3
    const unsigned l31  = lane & 31u;
    const unsigned l5   = lane >> 5;         // 0,1
    const unsigned qw   = wid >> 1;          // 0..3 : q-group (32 rows)
    const unsigned kh   = wid & 1u;          // 0,1  : key-half (32 keys)

    // XCD-aware mapping (R4 win: FETCH 417->43 MB)
    const unsigned xcd = blockIdx.x & 7u;
    const unsigned loc = blockIdx.x >> 3;        // 0..63
    const unsigned b   = xcd * 4u + (loc >> 4);  // batch
    const unsigned qt  = loc & 15u;              // q-tile in batch
    const unsigned qbase = qt * QBLK;

    // staging maps (512 threads) — verbatim R5
    const unsigned kr = tid >> 3, kc = tid & 7u;   // K: row 0..63, 32B chunk
    const unsigned vt = tid >> 4, vc = tid & 15u;  // V: key-pair 0..31, d-chunk

    // ---- Q -> 32x32 A-fragments from global (scale folded; R8-proven) ----
    s16x8 qf[4];
    {
        const float* qrow = qg + (size_t)(b * SQL + qbase + qw * 32 + l31) * DD;
        #pragma unroll
        for (int kk = 0; kk < 4; ++kk) {
            f32x4 f0 = *(const f32x4*)(qrow + kk * 16 + l5 * 8);
            f32x4 f1 = *(const f32x4*)(qrow + kk * 16 + l5 * 8 + 4);
            #pragma unroll
            for (int j = 0; j < 4; ++j) {
                qf[kk][j]     = (short)f2bf(f0[j] * 0.125f);
                qf[kk][j + 4] = (short)f2bf(f1[j] * 0.125f);
            }
        }
    }

    f32x4 acc_o[2][4];
    #pragma unroll
    for (int m = 0; m < 2; ++m)
        #pragma unroll
        for (int n = 0; n < 4; ++n) acc_o[m][n] = (f32x4){0.f, 0.f, 0.f, 0.f};

    const float* kbat = kg + (size_t)b * SKL * DD;
    const float* vbat = vg + (size_t)b * SKL * DD;

    auto stage = [&](int kt, int sel) {   // verbatim R5
        const float* ksrc = kbat + (size_t)kt * KBLK * DD;
        const float* vsrc = vbat + (size_t)kt * KBLK * DD;
        f32x4 k0 = *(const f32x4*)(ksrc + kr * DD + kc * 8);
        f32x4 k1 = *(const f32x4*)(ksrc + kr * DD + kc * 8 + 4);
        s16x8 h;
        #pragma unroll
        for (int j = 0; j < 4; ++j) {
            h[j]     = (short)f2bf(k0[j]);
            h[j + 4] = (short)f2bf(k1[j]);
        }
        *(s16x8*)(smem + KOFF + sel * 8192 + kr * 128 + ((kc * 16) ^ swzK(kr))) = h;
        f32x4 v0 = *(const f32x4*)(vsrc + (2 * vt) * DD + vc * 4);
        f32x4 v1 = *(const f32x4*)(vsrc + (2 * vt + 1) * DD + vc * 4);
        #pragma unroll
        for (int j = 0; j < 4; ++j) {
            unsigned d = vc * 4 + (unsigned)j;
            unsigned pack = (unsigned)f2bf(v0[j]) | ((unsigned)f2bf(v1[j]) << 16);
            *(unsigned*)(smem + VOFF + sel * 8192 + d * 128 + ((vt * 4) ^ swzV(d))) = pack;
        }
    };

    stage(0, 0);
    bar_lds();

    char* sb = smem + SOFF + wid * 2048;   // wave-private S_w: 32 x 64 B
    // attn base: q-row = qbase+qw*32+4*l5 (+crow(r)), col = kh*32+l31 (+kt*64)
    float* const aw = ag + (size_t)(b * SQL + qbase + qw * 32 + 4 * l5) * SKL
                         + kh * 32 + l31;

    for (int kt = 0; kt < NTILES; ++kt) {
        const int cur = kt & 1;
        if (kt + 1 < NTILES) stage(kt + 1, cur ^ 1);

        // ---- S_w = Q[32q] @ K[32k]^T via 32x32x16 (an: key-in-lanes) ----
        const char* kb = smem + KOFF + cur * 8192;
        f32x16 an = {0,0,0,0,0,0,0,0,0,0,0,0,0,0,0,0};
        #pragma unroll
        for (int kk = 0; kk < 4; ++kk) {
            unsigned row = kh * 32 + l31;
            s16x8 kf = *(const s16x8*)(kb + row * 128 +
                        ((kk * 32 + l5 * 16) ^ swzK(row)));
            an = __builtin_amdgcn_mfma_f32_32x32x16_bf16(qf[kk], kf, an, 0, 0, 0);
        }

        // ---- attn: direct fp32 NT stores, 128B row segments (R8-proven) ----
        {
            float* ap = aw + (size_t)kt * KBLK;
            #pragma unroll
            for (int r = 0; r < 16; ++r)
                __builtin_nontemporal_store(an[r],
                    ap + (size_t)((r & 3) + 8 * (r >> 2)) * SKL);
        }

        // ---- S_w -> wave-private LDS (bf16, rows 64 B) ----
        #pragma unroll
        for (int r = 0; r < 16; ++r) {
            unsigned q = (r & 3) + 8 * (r >> 2) + 4 * l5;
            *(unsigned short*)(sb + q * 64 + ((l31 * 2) ^ swzS(q))) = f2bf(an[r]);
        }

        // ---- O_partial += S_w[32q x 32k] @ V[32k x 64d] via 16x16x32 ----
        const char* vb = smem + VOFF + cur * 8192;
        #pragma unroll
        for (int m = 0; m < 2; ++m) {
            unsigned q = m * 16 + l15;
            s16x8 sa = *(const s16x8*)(sb + q * 64 + ((l4 * 16) ^ swzS(q)));
            #pragma unroll
            for (int nd = 0; nd < 4; ++nd) {
                unsigned row = nd * 16 + l15;
                s16x8 vf = *(const s16x8*)(vb + row * 128 +
                            ((kh * 64 + l4 * 16) ^ swzV(row)));
                acc_o[m][nd] = __builtin_amdgcn_mfma_f32_16x16x32_bf16(
                                   sa, vf, acc_o[m][nd], 0, 0, 0);
            }
        }

        bar_lds();   // dbuf flip (LDS-only; NT stores stay in flight)
    }

    // ---- O reduce across key-half pairs (kh=1 -> LDS, kh=0 adds+stores) ----
    float* red = (float*)smem + qw * 2048;   // 32 q x 64 d fp32 = 8 KB
    if (kh == 1) {
        #pragma unroll
        for (int m = 0; m < 2; ++m)
            #pragma unroll
            for (int nd = 0; nd < 4; ++nd)
                #pragma unroll
                for (int i = 0; i < 4; ++i) {
                    unsigned q = m * 16 + l4 * 4 + (unsigned)i;
                    unsigned d = nd * 16 + l15;
                    red[q * 64 + d] = acc_o[m][nd][i];
                }
    }
    bar_lds();
    if (kh == 0) {
        float* op = og + (size_t)(b * SQL + qbase + qw * 32) * DD;
        #pragma unroll
        for (int m = 0; m < 2; ++m)
            #pragma unroll
            for (int nd = 0; nd < 4; ++nd)
                #pragma unroll
                for (int i = 0; i < 4; ++i) {
                    unsigned q = m * 16 + l4 * 4 + (unsigned)i;
                    unsigned d = nd * 16 + l15;
                    float v = acc_o[m][nd][i] + red[q * 64 + d];
                    __builtin_nontemporal_store(v, op + (size_t)q * DD + d);
                }
    }
}

extern "C" void kernel_launch(void* const* d_in, const int* in_sizes, int n_in,
                              void* d_out, int out_size, void* d_ws, size_t ws_size,
                              hipStream_t stream) {
    const float* q = (const float*)d_in[0];
    const float* k = (const float*)d_in[1];
    const float* v = (const float*)d_in[2];
    float* outp  = (float*)d_out;                      // [32][2048][64]
    float* attnp = outp + (size_t)NB * SQL * DD;       // [32][2048][2048]
    sdpa_fused<<<dim3(NB * (SQL / QBLK)), dim3(512), 0, stream>>>(q, k, v, outp, attnp);
}

// Round 11
// 130.146 us; speedup vs baseline: 1.0667x; 1.0667x over previous
//
#include <hip/hip_runtime.h>
#include <hip/hip_bf16.h>

// ScaledDotProdAttn (no softmax): attn = (q@k^T)/8 ; out = attn@v
// B=32, SQ=SK=2048, D=64, fp32 in/out. d_out = [out] ++ [attn]
// R11: occupancy push. QBLK 128->64 => grid 1024 = 4 blocks/CU, LDS 40KB,
//      32 waves/CU target (VGPR<=64). 8 waves = 4 q-groups x 2 key-halves;
//      per-wave paths are R5-proven 16x16x32 frags + b64-readback dwordx4
//      attn stores. End-of-kernel O reduce across key-half pairs (reuses
//      K-dbuf LDS). Staging/swizzles/XCD-map/lgkm-barrier from R5/R9.

typedef __attribute__((ext_vector_type(4))) float        f32x4;
typedef __attribute__((ext_vector_type(8))) short        s16x8;
typedef __attribute__((ext_vector_type(2))) unsigned int u32x2;
typedef __attribute__((ext_vector_type(4))) unsigned int u32x4;

#define NB    32
#define SQL   2048
#define SKL   2048
#define DD    64
#define QBLK  64
#define KBLK  64
#define NTILES (SKL / KBLK)

// LDS (40 KB -> 4 blocks/CU with 512-thread blocks = 32 waves/CU):
//   [0    ,16384) K dbuf : 2 x (64 keys x 64 bf16), row stride 128 B, swzK
//   [16384,32768) V^T dbuf: 2 x (64 d x 64 keys bf16), row stride 128 B, swzV
//   [32768,40960) S priv : 8 waves x (16 q x 32 k bf16), row stride 64 B, swzS
//   epilogue: [0,16384) reused as 4 x 4 KB fp32 O-reduce scratch (per qh)
#define KOFF 0
#define VOFF 16384
#define SOFF 32768

__device__ __forceinline__ unsigned short f2bf(float f) {
    union { float f; unsigned u; } x; x.f = f;
    unsigned r = x.u + 0x7FFFu + ((x.u >> 16) & 1u);   // RNE
    return (unsigned short)(r >> 16);
}
// K/V swizzles (R5-proven, 128 B rows). S: 64 B rows, 4 q-rows per l4 group
// -> XOR byte bits 4..5 with q>>2 so l4 groups hit disjoint bank quads.
__device__ __forceinline__ unsigned swzK(unsigned k) { return (k & 7u) << 4; }
__device__ __forceinline__ unsigned swzV(unsigned d) { return (d & 7u) << 4; }
__device__ __forceinline__ unsigned swzS(unsigned q) { return ((q >> 2) & 3u) << 4; }

// Workgroup barrier draining LDS only (R9-proven: keeps NT stores lazy).
__device__ __forceinline__ void bar_lds() {
    asm volatile("s_waitcnt lgkmcnt(0)" ::: "memory");
    __builtin_amdgcn_s_barrier();
    asm volatile("" ::: "memory");
}

__global__ __launch_bounds__(512, 8)
void sdpa_fused(const float* __restrict__ qg, const float* __restrict__ kg,
                const float* __restrict__ vg, float* __restrict__ og,
                float* __restrict__ ag) {
    __shared__ __align__(16) char smem[40960];

    const unsigned tid  = threadIdx.x;
    const unsigned wid  = tid >> 6;          // 0..7
    const unsigned lane = tid & 63u;
    const unsigned l15  = lane & 15u;
    const unsigned l4   = lane >> 4;         // 0..3
    const unsigned qh   = wid >> 1;          // 0..3 : q-group (16 rows)
    const unsigned kh   = wid & 1u;          // 0,1  : key-half (32 keys)

    // XCD-aware mapping: grid 1024 = 8 XCD x 128; 4 batches x 32 qtiles each
    const unsigned xcd = blockIdx.x & 7u;
    const unsigned loc = blockIdx.x >> 3;        // 0..127
    const unsigned b   = xcd * 4u + (loc >> 5);  // batch
    const unsigned qt  = loc & 31u;              // q-tile in batch
    const unsigned qbase = qt * QBLK;

    // staging maps (512 threads) — verbatim R5
    const unsigned kr = tid >> 3, kc = tid & 7u;   // K: row 0..63, 32B chunk
    const unsigned vt = tid >> 4, vc = tid & 15u;  // V: key-pair 0..31, d-chunk

    // ---- Q -> A-fragments directly from global (scale folded in) ----
    s16x8 aq[2];
    {
        const float* qrow = qg + ((size_t)b * SQL + qbase + qh * 16 + l15) * DD;
        #pragma unroll
        for (int ks = 0; ks < 2; ++ks) {
            f32x4 f0 = *(const f32x4*)(qrow + ks * 32 + l4 * 8);
            f32x4 f1 = *(const f32x4*)(qrow + ks * 32 + l4 * 8 + 4);
            #pragma unroll
            for (int j = 0; j < 4; ++j) {
                aq[ks][j]     = (short)f2bf(f0[j] * 0.125f);
                aq[ks][j + 4] = (short)f2bf(f1[j] * 0.125f);
            }
        }
    }

    f32x4 acc_o[4];
    #pragma unroll
    for (int n = 0; n < 4; ++n) acc_o[n] = (f32x4){0.f, 0.f, 0.f, 0.f};

    const float* kbat = kg + (size_t)b * SKL * DD;
    const float* vbat = vg + (size_t)b * SKL * DD;

    auto stage = [&](int kt, int sel) {   // verbatim R5
        const float* ksrc = kbat + (size_t)kt * KBLK * DD;
        const float* vsrc = vbat + (size_t)kt * KBLK * DD;
        f32x4 k0 = *(const f32x4*)(ksrc + kr * DD + kc * 8);
        f32x4 k1 = *(const f32x4*)(ksrc + kr * DD + kc * 8 + 4);
        s16x8 h;
        #pragma unroll
        for (int j = 0; j < 4; ++j) {
            h[j]     = (short)f2bf(k0[j]);
            h[j + 4] = (short)f2bf(k1[j]);
        }
        *(s16x8*)(smem + KOFF + sel * 8192 + kr * 128 + ((kc * 16) ^ swzK(kr))) = h;
        f32x4 v0 = *(const f32x4*)(vsrc + (2 * vt) * DD + vc * 4);
        f32x4 v1 = *(const f32x4*)(vsrc + (2 * vt + 1) * DD + vc * 4);
        #pragma unroll
        for (int j = 0; j < 4; ++j) {
            unsigned d = vc * 4 + (unsigned)j;
            unsigned pack = (unsigned)f2bf(v0[j]) | ((unsigned)f2bf(v1[j]) << 16);
            *(unsigned*)(smem + VOFF + sel * 8192 + d * 128 + ((vt * 4) ^ swzV(d))) = pack;
        }
    };

    stage(0, 0);
    bar_lds();

    char* sb = smem + SOFF + wid * 1024;   // wave-private S_w: 16 x 64 B
    const unsigned rr = lane >> 3, cc = lane & 7u;  // attn readback map
    // attn row base for this wave; col base kh*32 within each k-tile
    float* const aw = ag + ((size_t)b * SQL + qbase + qh * 16) * SKL + kh * 32;

    for (int kt = 0; kt < NTILES; ++kt) {
        const int cur = kt & 1;
        if (kt + 1 < NTILES) stage(kt + 1, cur ^ 1);

        // ---- S_w = Q[16q] @ K[32k]^T (16x16x32, R5-proven frag paths) ----
        const char* kb = smem + KOFF + cur * 8192;
        f32x4 acc[2];
        acc[0] = (f32x4){0.f, 0.f, 0.f, 0.f};
        acc[1] = (f32x4){0.f, 0.f, 0.f, 0.f};
        #pragma unroll
        for (int ks = 0; ks < 2; ++ks)
            #pragma unroll
            for (int nk = 0; nk < 2; ++nk) {
                unsigned key = kh * 32 + nk * 16 + l15;
                s16x8 bk = *(const s16x8*)(kb + key * 128 +
                            ((ks * 64 + l4 * 16) ^ swzK(key)));
                acc[nk] = __builtin_amdgcn_mfma_f32_16x16x32_bf16(
                              aq[ks], bk, acc[nk], 0, 0, 0);
            }

        // ---- S_w -> wave-private LDS (bf16, 64 B rows) ----
        #pragma unroll
        for (int nk = 0; nk < 2; ++nk)
            #pragma unroll
            for (int i = 0; i < 4; ++i) {
                unsigned q   = l4 * 4 + (unsigned)i;
                unsigned key = nk * 16 + l15;
                *(unsigned short*)(sb + q * 64 + ((key * 2) ^ swzS(q))) =
                    f2bf(acc[nk][i]);
            }

        // ---- attn stores via readback: 8 lanes/row -> 128B segments ----
        {
            float* abase = aw + (size_t)kt * KBLK;
            #pragma unroll
            for (int h = 0; h < 2; ++h) {
                unsigned q  = h * 8 + rr;
                unsigned k4 = cc * 4;
                u32x2 p = *(const u32x2*)(sb + q * 64 + ((k4 * 2) ^ swzS(q)));
                u32x4 w;
                w[0] = p[0] << 16; w[1] = p[0] & 0xFFFF0000u;
                w[2] = p[1] << 16; w[3] = p[1] & 0xFFFF0000u;
                __builtin_nontemporal_store(w,
                    (u32x4*)(abase + (size_t)q * SKL + k4));
            }
        }

        // ---- O_partial += S_w[16q x 32k] @ V[32k x 64d] (one K-step) ----
        const char* vb = smem + VOFF + cur * 8192;
        s16x8 sa = *(const s16x8*)(sb + l15 * 64 + ((l4 * 16) ^ swzS(l15)));
        #pragma unroll
        for (int nd = 0; nd < 4; ++nd) {
            unsigned vrow = nd * 16 + l15;
            s16x8 vf = *(const s16x8*)(vb + vrow * 128 +
                        ((kh * 64 + l4 * 16) ^ swzV(vrow)));
            acc_o[nd] = __builtin_amdgcn_mfma_f32_16x16x32_bf16(
                            sa, vf, acc_o[nd], 0, 0, 0);
        }

        bar_lds();   // dbuf flip (LDS-only; NT stores stay in flight)
    }

    // ---- O reduce across key-half pairs (reuse K dbuf region) ----
    float* red = (float*)smem + qh * 1024;   // 16 q x 64 d fp32 = 4 KB
    if (kh == 1) {
        #pragma unroll
        for (int nd = 0; nd < 4; ++nd)
            #pragma unroll
            for (int i = 0; i < 4; ++i) {
                unsigned q = l4 * 4 + (unsigned)i;
                unsigned d = nd * 16 + l15;
                red[q * 64 + d] = acc_o[nd][i];
            }
    }
    bar_lds();
    if (kh == 0) {
        float* op = og + ((size_t)b * SQL + qbase + qh * 16) * DD;
        #pragma unroll
        for (int nd = 0; nd < 4; ++nd)
            #pragma unroll
            for (int i = 0; i < 4; ++i) {
                unsigned q = l4 * 4 + (unsigned)i;
                unsigned d = nd * 16 + l15;
                float v = acc_o[nd][i] + red[q * 64 + d];
                __builtin_nontemporal_store(v, op + (size_t)q * DD + d);
            }
    }
}

extern "C" void kernel_launch(void* const* d_in, const int* in_sizes, int n_in,
                              void* d_out, int out_size, void* d_ws, size_t ws_size,
                              hipStream_t stream) {
    const float* q = (const float*)d_in[0];
    const float* k = (const float*)d_in[1];
    const float* v = (const float*)d_in[2];
    float* outp  = (float*)d_out;                      // [32][2048][64]
    float* attnp = outp + (size_t)NB * SQL * DD;       // [32][2048][2048]
    sdpa_fused<<<dim3(NB * (SQL / QBLK)), dim3(512), 0, stream>>>(q, k, v, outp, attnp);
}